// Round 5
// baseline (971.822 us; speedup 1.0000x reference)
//
#include <hip/hip_runtime.h>
#include <math.h>

#define V  50257
#define H  1032
#define INW 2064
#define S  8192

// d_out flat layout (fp32): [output V][attn_context H][hidden H][attn_w S]
#define O_CTX  50257
#define O_HID  51289
#define O_ATTN 52321

// ws float offsets
#define OFF_HNEW 0                    // 1032
#define OFF_GX   1032                 // 3096
#define OFF_GH   4128                 // 3096
#define OFF_SC   7224                 // 8192 scores
#define OFF_W    15416                // 8192 attn weights
#define OFF_P1   23608                // 50257 p1acc
#define OFF_PART 73868                // 2*P2_B = 12566
#define OFF_L    86436                // 2 (pad to 4)
#define OFF_V    86440                // 1032 (zeroed)
#define OFF_CTXV 87472                // 1032 (zeroed)
#define OFF_CNT  88504                // 16 ints (zeroed)
#define ZERO_OFF OFF_V
#define ZERO_BYTES ((1032 + 1032 + 16) * 4)

// p1 row ranges per carrier kernel
#define P1A_END 16384
#define P1B_END 33280

#define GRU_B   774
#define VA_B    160
#define K2_P1B  2048   // rows [0, 16384), 2 rows/wave
#define SCORE_B 2048
#define K3_P1B  2112   // rows [16384, 33280)
#define CTX_B   640
#define K4_P1B  2123   // rows [33280, 50257)
#define P2_B    6283

__device__ __forceinline__ float waveReduceSum(float v) {
#pragma unroll
  for (int off = 32; off > 0; off >>= 1) v += __shfl_down(v, off);
  return v;  // valid in lane 0
}

__device__ __forceinline__ float dot4(const float4 a, const float4 b) {
  return a.x * b.x + a.y * b.y + a.z * b.z + a.w * b.w;
}

// K1: GRU matvec, wave j: gx[j]=W_ih[j].x, gh[j]=W_hh[j].h. Last block finalizes hnew.
__global__ __launch_bounds__(256) void gru_kernel(
    const int* __restrict__ word, const float* __restrict__ emb,
    const float* __restrict__ lc, const float* __restrict__ ph,
    const float* __restrict__ W_ih, const float* __restrict__ W_hh,
    const float* __restrict__ b_ih, const float* __restrict__ b_hh,
    float* __restrict__ ws, float* __restrict__ out) {
  __shared__ __align__(16) float xh[INW + H];
  __shared__ int isLast;
  float* gx = ws + OFF_GX;
  float* gh = ws + OFF_GH;
  float* hnew = ws + OFF_HNEW;
  int* cnt = (int*)(ws + OFF_CNT);
  int t = threadIdx.x, wv = t >> 6, lane = t & 63;
  int w0 = word[0];
  for (int i = t; i < INW; i += 256) xh[i] = (i < H) ? emb[(size_t)w0 * H + i] : lc[i - H];
  for (int i = t; i < H; i += 256) xh[INW + i] = ph[i];
  __syncthreads();
  int j = blockIdx.x * 4 + wv;  // [0, 3096)
  const float4* x4 = (const float4*)xh;
  const float4* h4 = (const float4*)(xh + INW);
  const float4* wi = (const float4*)(W_ih + (size_t)j * INW);
  float a0 = 0.f;
  for (int i = lane; i < INW / 4; i += 64) a0 += dot4(wi[i], x4[i]);
  const float4* wh = (const float4*)(W_hh + (size_t)j * H);
  float a1 = 0.f;
  for (int i = lane; i < H / 4; i += 64) a1 += dot4(wh[i], h4[i]);
  a0 = waveReduceSum(a0); a1 = waveReduceSum(a1);
  if (lane == 0) { gx[j] = a0; gh[j] = a1; }
  __threadfence();
  __syncthreads();
  if (t == 0) isLast = (atomicAdd(&cnt[0], 1) == GRU_B - 1);
  __syncthreads();
  if (isLast) {
    __threadfence();
    for (int k = t; k < H; k += 256) {
      float gr = gx[k] + gh[k] + b_ih[k] + b_hh[k];
      float gz = gx[H + k] + gh[H + k] + b_ih[H + k] + b_hh[H + k];
      float r  = 1.f / (1.f + expf(-gr));
      float z  = 1.f / (1.f + expf(-gz));
      float n  = tanhf(gx[2 * H + k] + b_ih[2 * H + k] + r * (gh[2 * H + k] + b_hh[2 * H + k]));
      float hv = (1.f - z) * n + z * ph[k];
      hnew[k] = hv;
      out[O_HID + k] = hv;
    }
  }
}

// K2: blocks [0,VA_B) va; rest p1 rows [0, P1A_END).
__global__ __launch_bounds__(256) void k2_kernel(
    const float* __restrict__ W_a, const float* __restrict__ W_out,
    const float* __restrict__ b_out, float* __restrict__ ws) {
  __shared__ __align__(16) float sh[H];
  float* hnew = ws + OFF_HNEW;
  float* v    = ws + OFF_V;
  float* p1acc = ws + OFF_P1;
  int b = blockIdx.x, t = threadIdx.x, wv = t >> 6, lane = t & 63;
  if (b < VA_B) {
    int ct = b % 5, jc = b / 5;
    int k = ct * 256 + t;
    if (k < H) {
      int j0 = jc * 33, j1 = min(j0 + 33, H);
      float acc = 0.f;
      for (int j = j0; j < j1; ++j) acc += W_a[(size_t)j * H + k] * hnew[j];
      atomicAdd(&v[k], acc);
    }
  } else {
    for (int i = t; i < H; i += 256) sh[i] = hnew[i];
    __syncthreads();
    const float4* sh4 = (const float4*)sh;
    int gw = (b - VA_B) * 4 + wv;
    int r0 = gw * 2;  // [0, 16384)
    const float4* R0 = (const float4*)(W_out + (size_t)r0 * INW);
    const float4* R1 = (const float4*)(W_out + (size_t)(r0 + 1) * INW);
    float a0 = 0.f, a1 = 0.f;
    for (int i = lane; i < H / 4; i += 64) {
      float4 c = sh4[i];
      a0 += dot4(R0[i], c);
      a1 += dot4(R1[i], c);
    }
    a0 = waveReduceSum(a0); a1 = waveReduceSum(a1);
    if (lane == 0) { p1acc[r0] = a0 + b_out[r0]; p1acc[r0 + 1] = a1 + b_out[r0 + 1]; }
  }
}

// K3: blocks [0,SCORE_B) scores (wave-per-row) + last-block softmax -> w, attn out;
// rest p1 rows [P1A_END, P1B_END).
__global__ __launch_bounds__(256) void k3_kernel(
    const float* __restrict__ enc, const float* __restrict__ W_out,
    const float* __restrict__ b_out, float* __restrict__ ws,
    float* __restrict__ out) {
  __shared__ __align__(16) float sh[H];
  __shared__ float red[256];
  __shared__ int isLast;
  float* hnew = ws + OFF_HNEW;
  float* v    = ws + OFF_V;
  float* sc   = ws + OFF_SC;
  float* w    = ws + OFF_W;
  float* p1acc = ws + OFF_P1;
  int* cnt = (int*)(ws + OFF_CNT);
  int b = blockIdx.x, t = threadIdx.x, wv = t >> 6, lane = t & 63;
  if (b < SCORE_B) {
    int s = b * 4 + wv;
    const float4* row = (const float4*)(enc + (size_t)s * H);
    const float4* v4  = (const float4*)v;
    float acc = 0.f;
    for (int i = lane; i < H / 4; i += 64) acc += dot4(row[i], v4[i]);
    acc = waveReduceSum(acc);
    if (lane == 0) sc[s] = acc;
    __threadfence();
    __syncthreads();
    if (t == 0) isLast = (atomicAdd(&cnt[1], 1) == SCORE_B - 1);
    __syncthreads();
    if (isLast) {
      __threadfence();
      float m = -3.4e38f;
      for (int i = t; i < S; i += 256) m = fmaxf(m, sc[i]);
      red[t] = m; __syncthreads();
      for (int off = 128; off; off >>= 1) {
        if (t < off) red[t] = fmaxf(red[t], red[t + off]);
        __syncthreads();
      }
      m = red[0]; __syncthreads();
      float s2 = 0.f;
      for (int i = t; i < S; i += 256) s2 += expf(sc[i] - m);
      red[t] = s2; __syncthreads();
      for (int off = 128; off; off >>= 1) {
        if (t < off) red[t] += red[t + off];
        __syncthreads();
      }
      float inv = 1.f / red[0];
      for (int i = t; i < S; i += 256) {
        float wt = expf(sc[i] - m) * inv;
        w[i] = wt;
        out[O_ATTN + i] = wt;
      }
    }
  } else {
    for (int i = t; i < H; i += 256) sh[i] = hnew[i];
    __syncthreads();
    const float4* sh4 = (const float4*)sh;
    int gw = (b - SCORE_B) * 4 + wv;
    int r0 = P1A_END + gw * 2;  // [16384, 33280)
    const float4* R0 = (const float4*)(W_out + (size_t)r0 * INW);
    const float4* R1 = (const float4*)(W_out + (size_t)(r0 + 1) * INW);
    float a0 = 0.f, a1 = 0.f;
    for (int i = lane; i < H / 4; i += 64) {
      float4 c = sh4[i];
      a0 += dot4(R0[i], c);
      a1 += dot4(R1[i], c);
    }
    a0 = waveReduceSum(a0); a1 = waveReduceSum(a1);
    if (lane == 0) { p1acc[r0] = a0 + b_out[r0]; p1acc[r0 + 1] = a1 + b_out[r0 + 1]; }
  }
}

// K4: blocks [0,CTX_B) ctx weighted sum; rest p1 rows [P1B_END, V).
__global__ __launch_bounds__(256) void k4_kernel(
    const float* __restrict__ enc, const float* __restrict__ W_out,
    const float* __restrict__ b_out, float* __restrict__ ws) {
  __shared__ __align__(16) float sh[H];
  __shared__ float wsh[64];
  float* hnew = ws + OFF_HNEW;
  float* w    = ws + OFF_W;
  float* ctxv = ws + OFF_CTXV;
  float* p1acc = ws + OFF_P1;
  int b = blockIdx.x, t = threadIdx.x, wv = t >> 6, lane = t & 63;
  if (b < CTX_B) {
    int ct = b % 5, yc = b / 5;
    int s0 = yc * 64;
    if (t < 64) wsh[t] = w[s0 + t];
    __syncthreads();
    int k = ct * 256 + t;
    if (k < H) {
      float acc = 0.f;
      for (int si = 0; si < 64; ++si) acc += wsh[si] * enc[(size_t)(s0 + si) * H + k];
      atomicAdd(&ctxv[k], acc);
    }
  } else {
    for (int i = t; i < H; i += 256) sh[i] = hnew[i];
    __syncthreads();
    const float4* sh4 = (const float4*)sh;
    int gw = (b - CTX_B) * 4 + wv;
    int r0 = P1B_END + gw * 2;  // [33280, 50257)
#pragma unroll
    for (int q = 0; q < 2; ++q) {
      int r = r0 + q;
      if (r < V) {
        const float4* R = (const float4*)(W_out + (size_t)r * INW);
        float a = 0.f;
        for (int i = lane; i < H / 4; i += 64) a += dot4(R[i], sh4[i]);
        a = waveReduceSum(a);
        if (lane == 0) p1acc[r] = a + b_out[r];
      }
    }
  }
}

// K5: p2 ctx-half dot + p1acc -> logits + lse partials; last block -> Lval.
__global__ __launch_bounds__(256) void p2_kernel(
    const float* __restrict__ W_out, float* __restrict__ ws,
    float* __restrict__ out) {
  __shared__ __align__(16) float sh[H];
  __shared__ float wred[4][2];
  __shared__ float redm[256], reds[256];
  __shared__ int isLast;
  float* ctxv = ws + OFF_CTXV;
  float* p1acc = ws + OFF_P1;
  float* partials = ws + OFF_PART;
  float* Lval = ws + OFF_L;
  int* cnt = (int*)(ws + OFF_CNT);
  int b = blockIdx.x, t = threadIdx.x, wv = t >> 6, lane = t & 63;
  for (int i = t; i < H; i += 256) sh[i] = ctxv[i];
  __syncthreads();
  if (b == 0) for (int i = t; i < H; i += 256) out[O_CTX + i] = sh[i];
  const float4* sh4 = (const float4*)sh;
  int gw = b * 4 + wv;
  int r0 = gw * 2;
  float lm = -3.4e38f, ls = 0.f;
#pragma unroll
  for (int q = 0; q < 2; ++q) {
    int r = r0 + q;
    if (r < V) {
      const float4* R = (const float4*)(W_out + (size_t)r * INW + H);
      float a = 0.f;
      for (int i = lane; i < H / 4; i += 64) a += dot4(R[i], sh4[i]);
      a = waveReduceSum(a);
      if (lane == 0) {
        float x = p1acc[r] + a;
        out[r] = x;
        float nm = fmaxf(lm, x);
        ls = ls * expf(lm - nm) + expf(x - nm);
        lm = nm;
      }
    }
  }
  if (lane == 0) { wred[wv][0] = lm; wred[wv][1] = ls; }
  __syncthreads();
  if (t == 0) {
    float m = wred[0][0], s = wred[0][1];
    for (int q = 1; q < 4; ++q) {
      float nm = fmaxf(m, wred[q][0]);
      s = s * expf(m - nm) + wred[q][1] * expf(wred[q][0] - nm);
      m = nm;
    }
    partials[2 * b] = m;
    partials[2 * b + 1] = s;
  }
  __threadfence();
  __syncthreads();
  if (t == 0) isLast = (atomicAdd(&cnt[2], 1) == P2_B - 1);
  __syncthreads();
  if (isLast) {
    __threadfence();
    float m = -3.4e38f, s = 0.f;
    for (int i = t; i < P2_B; i += 256) {
      float bm = partials[2 * i], bs = partials[2 * i + 1];
      float nm = fmaxf(m, bm);
      s = s * expf(m - nm) + bs * expf(bm - nm);
      m = nm;
    }
    redm[t] = m; reds[t] = s; __syncthreads();
    for (int off = 128; off; off >>= 1) {
      if (t < off) {
        float m2 = redm[t + off], s2 = reds[t + off];
        float nm = fmaxf(redm[t], m2);
        reds[t] = reds[t] * expf(redm[t] - nm) + s2 * expf(m2 - nm);
        redm[t] = nm;
      }
      __syncthreads();
    }
    if (t == 0) Lval[0] = redm[0] + logf(reds[0]);
  }
}

// K6: out[i] -= L
__global__ __launch_bounds__(256) void apply_kernel(
    float* __restrict__ out, const float* __restrict__ ws) {
  float L = (ws + OFF_L)[0];
  int i = blockIdx.x * 256 + threadIdx.x;
  if (i < V) out[i] -= L;
}

extern "C" void kernel_launch(void* const* d_in, const int* in_sizes, int n_in,
                              void* d_out, int out_size, void* d_ws, size_t ws_size,
                              hipStream_t stream) {
  const int*   word  = (const int*)d_in[0];
  const float* lc    = (const float*)d_in[1];
  const float* ph    = (const float*)d_in[2];
  const float* enc   = (const float*)d_in[3];
  const float* emb   = (const float*)d_in[4];
  const float* W_ih  = (const float*)d_in[5];
  const float* W_hh  = (const float*)d_in[6];
  const float* b_ih  = (const float*)d_in[7];
  const float* b_hh  = (const float*)d_in[8];
  const float* W_a   = (const float*)d_in[9];
  // d_in[10] = b_a: unused — constant shift of all attention scores, cancels in softmax.
  const float* W_out = (const float*)d_in[11];
  const float* b_out = (const float*)d_in[12];
  float* out = (float*)d_out;
  float* ws  = (float*)d_ws;

  hipMemsetAsync(ws + ZERO_OFF, 0, ZERO_BYTES, stream);
  gru_kernel<<<GRU_B, 256, 0, stream>>>(word, emb, lc, ph, W_ih, W_hh, b_ih, b_hh, ws, out);
  k2_kernel<<<VA_B + K2_P1B, 256, 0, stream>>>(W_a, W_out, b_out, ws);
  k3_kernel<<<SCORE_B + K3_P1B, 256, 0, stream>>>(enc, W_out, b_out, ws, out);
  k4_kernel<<<CTX_B + K4_P1B, 256, 0, stream>>>(enc, W_out, b_out, ws);
  p2_kernel<<<P2_B, 256, 0, stream>>>(W_out, ws, out);
  apply_kernel<<<(V + 255) / 256, 256, 0, stream>>>(out, ws);
}

// Round 6
// 177.701 us; speedup vs baseline: 5.4689x; 5.4689x over previous
//
#include <hip/hip_runtime.h>
#include <math.h>

#define V  50257
#define H  1032
#define INW 2064
#define S  8192

// d_out flat layout (fp32): [output V][attn_context H][hidden H][attn_w S]
#define O_CTX  50257
#define O_HID  51289
#define O_ATTN 52321

// ws float offsets
#define OFF_HNEW 0        // 1032
#define OFF_GX   1032     // 3096
#define OFF_GH   4128     // 3096
#define OFF_SC   7224     // 8192 scores
#define OFF_V    15416    // 1032 (zeroed by gru_fin)
#define OFF_CTXV 16448    // 1032 (zeroed by gru_fin)
#define OFF_P1   17480    // 50257 p1acc
#define OFF_PART 67737    // 2*P2_B

// p1 row range boundaries
#define P1A_END 16384
#define P1B_END 33280

#define GRU_B   774
#define VA_B    80
#define K3_P1B  2048   // rows [0, 16384): 2048 blk * 4 waves * 2 rows
#define SCORE_B 2048
#define K4_P1B  2112   // rows [16384, 33280)
#define CTX_B   640
#define K5_P1B  2123   // rows [33280, 50257)
#define P2_B    6283
#define NPART   P2_B

__device__ __forceinline__ float waveReduceSum(float v) {
#pragma unroll
  for (int off = 32; off > 0; off >>= 1) v += __shfl_down(v, off);
  return v;  // valid in lane 0
}

__device__ __forceinline__ float dot4(const float4 a, const float4 b) {
  return a.x * b.x + a.y * b.y + a.z * b.z + a.w * b.w;
}

// K1: GRU matvec only. wave j: gx[j] = W_ih[j].x, gh[j] = W_hh[j].h. No fences.
__global__ __launch_bounds__(256) void gru_mv_kernel(
    const int* __restrict__ word, const float* __restrict__ emb,
    const float* __restrict__ lc, const float* __restrict__ ph,
    const float* __restrict__ W_ih, const float* __restrict__ W_hh,
    float* __restrict__ ws) {
  __shared__ __align__(16) float xh[INW + H];
  float* gx = ws + OFF_GX;
  float* gh = ws + OFF_GH;
  int t = threadIdx.x, wv = t >> 6, lane = t & 63;
  int w0 = word[0];
  for (int i = t; i < INW; i += 256) xh[i] = (i < H) ? emb[(size_t)w0 * H + i] : lc[i - H];
  for (int i = t; i < H; i += 256) xh[INW + i] = ph[i];
  __syncthreads();
  int j = blockIdx.x * 4 + wv;  // [0, 3096)
  const float4* x4 = (const float4*)xh;
  const float4* h4 = (const float4*)(xh + INW);
  const float4* wi = (const float4*)(W_ih + (size_t)j * INW);
  float a0 = 0.f;
  for (int i = lane; i < INW / 4; i += 64) a0 += dot4(wi[i], x4[i]);
  const float4* wh = (const float4*)(W_hh + (size_t)j * H);
  float a1 = 0.f;
  for (int i = lane; i < H / 4; i += 64) a1 += dot4(wh[i], h4[i]);
  a0 = waveReduceSum(a0); a1 = waveReduceSum(a1);
  if (lane == 0) { gx[j] = a0; gh[j] = a1; }
}

// K2: GRU finalize (elementwise, 4 blocks x 258 slice). Also zeroes v and ctx slices.
__global__ __launch_bounds__(256) void gru_fin_kernel(
    const float* __restrict__ ph, const float* __restrict__ b_ih,
    const float* __restrict__ b_hh, float* __restrict__ ws,
    float* __restrict__ out) {
  float* gx   = ws + OFF_GX;
  float* gh   = ws + OFF_GH;
  float* hnew = ws + OFF_HNEW;
  float* v    = ws + OFF_V;
  float* ctxv = ws + OFF_CTXV;
  int t = threadIdx.x, b = blockIdx.x;
  for (int kk = t; kk < 258; kk += 256) {
    int k = b * 258 + kk;
    float gr = gx[k] + gh[k] + b_ih[k] + b_hh[k];
    float gz = gx[H + k] + gh[H + k] + b_ih[H + k] + b_hh[H + k];
    float r  = 1.f / (1.f + expf(-gr));
    float z  = 1.f / (1.f + expf(-gz));
    float n  = tanhf(gx[2 * H + k] + b_ih[2 * H + k] + r * (gh[2 * H + k] + b_hh[2 * H + k]));
    float hv = (1.f - z) * n + z * ph[k];
    hnew[k] = hv;
    out[O_HID + k] = hv;
    v[k] = 0.f;
    ctxv[k] = 0.f;
  }
}

// Carrier helper: hnew-half dot for 2 consecutive rows per wave.
__device__ __forceinline__ void p1_rows(
    const float* __restrict__ W_out, const float* __restrict__ b_out,
    const float4* __restrict__ sh4, float* __restrict__ p1acc,
    int r0, int lane) {
  const float4* R0 = (const float4*)(W_out + (size_t)r0 * INW);
  const float4* R1 = (const float4*)(W_out + (size_t)(r0 + 1) * INW);
  float a0 = 0.f, a1 = 0.f;
  bool ok1 = (r0 + 1) < V;
  for (int i = lane; i < H / 4; i += 64) {
    float4 c = sh4[i];
    a0 += dot4(R0[i], c);
    if (ok1) a1 += dot4(R1[i], c);
  }
  a0 = waveReduceSum(a0); a1 = waveReduceSum(a1);
  if (lane == 0) {
    if (r0 < V)     p1acc[r0]     = a0 + b_out[r0];
    if (r0 + 1 < V) p1acc[r0 + 1] = a1 + b_out[r0 + 1];
  }
}

// K3: blocks [0,VA_B) va: v[k] += W_a^T hnew; rest: p1 rows [0, P1A_END).
__global__ __launch_bounds__(256) void k3_kernel(
    const float* __restrict__ W_a, const float* __restrict__ W_out,
    const float* __restrict__ b_out, float* __restrict__ ws) {
  __shared__ __align__(16) float sh[H];
  float* hnew  = ws + OFF_HNEW;
  float* v     = ws + OFF_V;
  float* p1acc = ws + OFF_P1;
  int b = blockIdx.x, t = threadIdx.x, wv = t >> 6, lane = t & 63;
  if (b < VA_B) {
    int ct = b % 5, jc = b / 5;
    int k = ct * 256 + t;
    if (k < H) {
      int j0 = jc * 65, j1 = min(j0 + 65, H);
      float acc = 0.f;
      for (int j = j0; j < j1; ++j) acc += W_a[(size_t)j * H + k] * hnew[j];
      atomicAdd(&v[k], acc);
    }
  } else {
    for (int i = t; i < H; i += 256) sh[i] = hnew[i];
    __syncthreads();
    int gw = (b - VA_B) * 4 + wv;
    p1_rows(W_out, b_out, (const float4*)sh, p1acc, gw * 2, lane);
  }
}

// K4: blocks [0,SCORE_B) scores (wave-per-row); rest: p1 rows [P1A_END, P1B_END).
__global__ __launch_bounds__(256) void k4_kernel(
    const float* __restrict__ enc, const float* __restrict__ W_out,
    const float* __restrict__ b_out, float* __restrict__ ws) {
  __shared__ __align__(16) float sh[H];
  float* hnew  = ws + OFF_HNEW;
  float* v     = ws + OFF_V;
  float* sc    = ws + OFF_SC;
  float* p1acc = ws + OFF_P1;
  int b = blockIdx.x, t = threadIdx.x, wv = t >> 6, lane = t & 63;
  if (b < SCORE_B) {
    int s = b * 4 + wv;
    const float4* row = (const float4*)(enc + (size_t)s * H);
    const float4* v4  = (const float4*)v;
    float acc = 0.f;
    for (int i = lane; i < H / 4; i += 64) acc += dot4(row[i], v4[i]);
    acc = waveReduceSum(acc);
    if (lane == 0) sc[s] = acc;
  } else {
    for (int i = t; i < H; i += 256) sh[i] = hnew[i];
    __syncthreads();
    int gw = (b - SCORE_B) * 4 + wv;
    p1_rows(W_out, b_out, (const float4*)sh, p1acc, P1A_END + gw * 2, lane);
  }
}

// K5: blocks [0,CTX_B) ctx (softmax recomputed per block from sc — deterministic,
// L2-resident); col-tile 0 writes attn weights. Rest: p1 rows [P1B_END, V).
__global__ __launch_bounds__(256) void k5_kernel(
    const float* __restrict__ enc, const float* __restrict__ W_out,
    const float* __restrict__ b_out, float* __restrict__ ws,
    float* __restrict__ out) {
  __shared__ __align__(16) float sh[H];
  float* hnew  = ws + OFF_HNEW;
  float* sc    = ws + OFF_SC;
  float* ctxv  = ws + OFF_CTXV;
  float* p1acc = ws + OFF_P1;
  int b = blockIdx.x, t = threadIdx.x, wv = t >> 6, lane = t & 63;
  if (b < CTX_B) {
    __shared__ float red[256];
    __shared__ float wsh[64];
    float m = -3.4e38f;
    for (int i = t; i < S; i += 256) m = fmaxf(m, sc[i]);
    red[t] = m; __syncthreads();
    for (int off = 128; off; off >>= 1) {
      if (t < off) red[t] = fmaxf(red[t], red[t + off]);
      __syncthreads();
    }
    m = red[0]; __syncthreads();
    float s = 0.f;
    for (int i = t; i < S; i += 256) s += expf(sc[i] - m);
    red[t] = s; __syncthreads();
    for (int off = 128; off; off >>= 1) {
      if (t < off) red[t] += red[t + off];
      __syncthreads();
    }
    float inv = 1.f / red[0];
    int ct = b % 5, yc = b / 5;
    int s0 = yc * 64;
    if (t < 64) wsh[t] = expf(sc[s0 + t] - m) * inv;
    __syncthreads();
    if (ct == 0 && t < 64) out[O_ATTN + s0 + t] = wsh[t];
    int k = ct * 256 + t;
    if (k < H) {
      float acc = 0.f;
      for (int si = 0; si < 64; ++si) acc += wsh[si] * enc[(size_t)(s0 + si) * H + k];
      atomicAdd(&ctxv[k], acc);
    }
  } else {
    for (int i = t; i < H; i += 256) sh[i] = hnew[i];
    __syncthreads();
    int gw = (b - CTX_B) * 4 + wv;
    p1_rows(W_out, b_out, (const float4*)sh, p1acc, P1B_END + gw * 2, lane);
  }
}

// K6: p2 = ctx-half dot + p1acc -> logits + per-block lse partials. No fences.
__global__ __launch_bounds__(256) void p2_kernel(
    const float* __restrict__ W_out, float* __restrict__ ws,
    float* __restrict__ out) {
  __shared__ __align__(16) float sh[H];
  __shared__ float wred[4][2];
  float* ctxv     = ws + OFF_CTXV;
  float* p1acc    = ws + OFF_P1;
  float* partials = ws + OFF_PART;
  int b = blockIdx.x, t = threadIdx.x, wv = t >> 6, lane = t & 63;
  for (int i = t; i < H; i += 256) sh[i] = ctxv[i];
  __syncthreads();
  if (b == 0) for (int i = t; i < H; i += 256) out[O_CTX + i] = sh[i];
  const float4* sh4 = (const float4*)sh;
  int gw = b * 4 + wv;
  int r0 = gw * 2;
  const float4* R0 = (const float4*)(W_out + (size_t)r0 * INW + H);
  const float4* R1 = (const float4*)(W_out + (size_t)(r0 + 1) * INW + H);
  bool ok0 = r0 < V, ok1 = (r0 + 1) < V;
  float a0 = 0.f, a1 = 0.f;
  for (int i = lane; i < H / 4; i += 64) {
    float4 c = sh4[i];
    if (ok0) a0 += dot4(R0[i], c);
    if (ok1) a1 += dot4(R1[i], c);
  }
  a0 = waveReduceSum(a0); a1 = waveReduceSum(a1);
  float lm = -3.4e38f, ls = 0.f;
  if (lane == 0) {
    if (ok0) {
      float x = p1acc[r0] + a0;
      out[r0] = x;
      lm = x; ls = 1.f;
    }
    if (ok1) {
      float x = p1acc[r0 + 1] + a1;
      out[r0 + 1] = x;
      float nm = fmaxf(lm, x);
      ls = ls * expf(lm - nm) + expf(x - nm);
      lm = nm;
    }
    wred[wv][0] = lm; wred[wv][1] = ls;
  }
  __syncthreads();
  if (t == 0) {
    float m = wred[0][0], s = wred[0][1];
    for (int q = 1; q < 4; ++q) {
      float nm = fmaxf(m, wred[q][0]);
      s = s * expf(m - nm) + wred[q][1] * expf(wred[q][0] - nm);
      m = nm;
    }
    partials[2 * b] = m;
    partials[2 * b + 1] = s;
  }
}

// K7: apply — redundant partial combine per block (deterministic), subtract lse.
__global__ __launch_bounds__(256) void apply_kernel(
    float* __restrict__ out, const float* __restrict__ ws) {
  __shared__ float mm[256], ssv[256];
  const float* partials = ws + OFF_PART;
  int t = threadIdx.x;
  float m = -3.4e38f, s = 0.f;
  for (int i = t; i < NPART; i += 256) {
    float bm = partials[2 * i], bs = partials[2 * i + 1];
    float nm = fmaxf(m, bm);
    s = s * expf(m - nm) + bs * expf(bm - nm);
    m = nm;
  }
  mm[t] = m; ssv[t] = s; __syncthreads();
  for (int off = 128; off; off >>= 1) {
    if (t < off) {
      float m2 = mm[t + off], s2 = ssv[t + off];
      float nm = fmaxf(mm[t], m2);
      ssv[t] = ssv[t] * expf(mm[t] - nm) + s2 * expf(m2 - nm);
      mm[t] = nm;
    }
    __syncthreads();
  }
  float L = mm[0] + logf(ssv[0]);
  int i = blockIdx.x * 256 + t;
  if (i < V) out[i] -= L;
}

extern "C" void kernel_launch(void* const* d_in, const int* in_sizes, int n_in,
                              void* d_out, int out_size, void* d_ws, size_t ws_size,
                              hipStream_t stream) {
  const int*   word  = (const int*)d_in[0];
  const float* lc    = (const float*)d_in[1];
  const float* ph    = (const float*)d_in[2];
  const float* enc   = (const float*)d_in[3];
  const float* emb   = (const float*)d_in[4];
  const float* W_ih  = (const float*)d_in[5];
  const float* W_hh  = (const float*)d_in[6];
  const float* b_ih  = (const float*)d_in[7];
  const float* b_hh  = (const float*)d_in[8];
  const float* W_a   = (const float*)d_in[9];
  // d_in[10] = b_a: unused — constant shift of all attention scores, cancels in softmax.
  const float* W_out = (const float*)d_in[11];
  const float* b_out = (const float*)d_in[12];
  float* out = (float*)d_out;
  float* ws  = (float*)d_ws;

  gru_mv_kernel<<<GRU_B, 256, 0, stream>>>(word, emb, lc, ph, W_ih, W_hh, ws);
  gru_fin_kernel<<<4, 256, 0, stream>>>(ph, b_ih, b_hh, ws, out);
  k3_kernel<<<VA_B + K3_P1B, 256, 0, stream>>>(W_a, W_out, b_out, ws);
  k4_kernel<<<SCORE_B + K4_P1B, 256, 0, stream>>>(enc, W_out, b_out, ws);
  k5_kernel<<<CTX_B + K5_P1B, 256, 0, stream>>>(enc, W_out, b_out, ws, out);
  p2_kernel<<<P2_B, 256, 0, stream>>>(W_out, ws, out);
  apply_kernel<<<(V + 255) / 256, 256, 0, stream>>>(out, ws);
}

// Round 7
// 143.518 us; speedup vs baseline: 6.7714x; 1.2382x over previous
//
#include <hip/hip_runtime.h>
#include <math.h>

#define V  50257
#define H  1032
#define INW 2064
#define S  8192

// d_out flat layout (fp32): [output V][attn_context H][hidden H][attn_w S]
#define O_CTX  50257
#define O_HID  51289
#define O_ATTN 52321

// ws float offsets
#define OFF_GXP  0        // 2*3096 gx partials (chunk-major)
#define OFF_GHP  6192     // 2*3096 gh partials
#define OFF_HNEW 12384    // 1032
#define OFF_V    13416    // 1032 (zeroed by K1 block 0)
#define OFF_CTXV 14448    // 1032 (zeroed by K1 block 1)
#define OFF_SC   15480    // 8192 scores
#define OFF_PART 23672    // 2*NPART lse partials

#define GRU_B   1548      // 6192 waves = 3096 rows x 2 K-chunks
#define VA_B    80        // 5 col-tiles x 16 j-chunks
#define NPART   2048      // logits blocks / partial pairs

__device__ __forceinline__ float waveReduceSum(float v) {
#pragma unroll
  for (int off = 32; off > 0; off >>= 1) v += __shfl_down(v, off);
  return v;  // valid in lane 0
}

__device__ __forceinline__ float dot4(const float4 a, const float4 b) {
  return a.x * b.x + a.y * b.y + a.z * b.z + a.w * b.w;
}

// K1: GRU matvec partials. Wave g = b*4+wv: row j = g>>1, K-chunk c = g&1.
// gxp[c][j] = W_ih[j, c*1032 : (c+1)*1032) . x[...], ghp[c][j] similar (516-chunks).
// Blocks 0/1 zero v/ctxv for later atomics.
__global__ __launch_bounds__(256) void gru_mv_kernel(
    const int* __restrict__ word, const float* __restrict__ emb,
    const float* __restrict__ lc, const float* __restrict__ ph,
    const float* __restrict__ W_ih, const float* __restrict__ W_hh,
    float* __restrict__ ws) {
  __shared__ __align__(16) float xh[INW + H];
  float* gxp = ws + OFF_GXP;
  float* ghp = ws + OFF_GHP;
  int t = threadIdx.x, wv = t >> 6, lane = t & 63, b = blockIdx.x;
  if (b == 0) for (int i = t; i < H; i += 256) (ws + OFF_V)[i] = 0.f;
  if (b == 1) for (int i = t; i < H; i += 256) (ws + OFF_CTXV)[i] = 0.f;
  int w0 = word[0];
  for (int i = t; i < INW; i += 256) xh[i] = (i < H) ? emb[(size_t)w0 * H + i] : lc[i - H];
  for (int i = t; i < H; i += 256) xh[INW + i] = ph[i];
  __syncthreads();
  int g = b * 4 + wv;            // [0, 6192)
  int j = g >> 1, c = g & 1;     // row, K-chunk
  // W_ih chunk: 258 float4 starting at j*2064 + c*1032
  const float4* wi = (const float4*)(W_ih + (size_t)j * INW + c * (INW / 2));
  const float4* x4 = (const float4*)(xh + c * (INW / 2));
  float a0 = 0.f;
  for (int i = lane; i < INW / 8; i += 64) a0 += dot4(wi[i], x4[i]);   // 258 f4
  // W_hh chunk: 129 float4 starting at j*1032 + c*516
  const float4* wh = (const float4*)(W_hh + (size_t)j * H + c * (H / 2));
  const float4* h4 = (const float4*)(xh + INW + c * (H / 2));
  float a1 = 0.f;
  for (int i = lane; i < H / 8; i += 64) a1 += dot4(wh[i], h4[i]);     // 129 f4
  a0 = waveReduceSum(a0); a1 = waveReduceSum(a1);
  if (lane == 0) { gxp[c * 3096 + j] = a0; ghp[c * 3096 + j] = a1; }
}

__device__ __forceinline__ float gru_elem(
    const float* __restrict__ gxp, const float* __restrict__ ghp,
    const float* __restrict__ b_ih, const float* __restrict__ b_hh,
    const float* __restrict__ ph, int k) {
  float gxr = gxp[k] + gxp[3096 + k],           ghr = ghp[k] + ghp[3096 + k];
  float gxz = gxp[H + k] + gxp[3096 + H + k],   ghz = ghp[H + k] + ghp[3096 + H + k];
  float gxn = gxp[2 * H + k] + gxp[3096 + 2 * H + k];
  float ghn = ghp[2 * H + k] + ghp[3096 + 2 * H + k];
  float r = 1.f / (1.f + expf(-(gxr + ghr + b_ih[k] + b_hh[k])));
  float z = 1.f / (1.f + expf(-(gxz + ghz + b_ih[H + k] + b_hh[H + k])));
  float n = tanhf(gxn + b_ih[2 * H + k] + r * (ghn + b_hh[2 * H + k]));
  return (1.f - z) * n + z * ph[k];
}

// K2: blocks [0,VA_B): v[k] += sum_{j in chunk} W_a[j][k] * hnew[j], with the
// needed hnew slice finalized redundantly in-block from the K1 partials.
// Blocks [VA_B, VA_B+4): finalize + write hnew to ws and hid to d_out.
__global__ __launch_bounds__(256) void vafin_kernel(
    const float* __restrict__ W_a, const float* __restrict__ ph,
    const float* __restrict__ b_ih, const float* __restrict__ b_hh,
    float* __restrict__ ws, float* __restrict__ out) {
  __shared__ float hsh[65];
  const float* gxp = ws + OFF_GXP;
  const float* ghp = ws + OFF_GHP;
  int b = blockIdx.x, t = threadIdx.x;
  if (b < VA_B) {
    int ct = b % 5, jc = b / 5;
    int j0 = jc * 65;
    int nj = min(65, H - j0);
    if (t < nj) hsh[t] = gru_elem(gxp, ghp, b_ih, b_hh, ph, j0 + t);
    __syncthreads();
    int k = ct * 256 + t;
    if (k < H) {
      float acc = 0.f;
      for (int j = 0; j < nj; ++j) acc += W_a[(size_t)(j0 + j) * H + k] * hsh[j];
      atomicAdd(ws + OFF_V + k, acc);
    }
  } else {
    int base = (b - VA_B) * 258;
    for (int kk = t; kk < 258; kk += 256) {
      int k = base + kk;
      float hv = gru_elem(gxp, ghp, b_ih, b_hh, ph, k);
      (ws + OFF_HNEW)[k] = hv;
      out[O_HID + k] = hv;
    }
  }
}

// K3: scores[s] = enc[s,:] . v  (b_a dropped: constant shift cancels in softmax)
__global__ __launch_bounds__(256) void scores_kernel(
    const float* __restrict__ enc, float* __restrict__ ws) {
  int t = threadIdx.x, wv = t >> 6, lane = t & 63;
  int s = blockIdx.x * 4 + wv;  // 2048 blocks -> 8192 rows
  const float4* row = (const float4*)(enc + (size_t)s * H);
  const float4* v4  = (const float4*)(ws + OFF_V);
  float acc = 0.f;
  for (int i = lane; i < H / 4; i += 64) acc += dot4(row[i], v4[i]);
  acc = waveReduceSum(acc);
  if (lane == 0) (ws + OFF_SC)[s] = acc;
}

// K4: ctx[k] = sum_s w[s]*enc[s][k], softmax recomputed per block (deterministic,
// scores L2-resident). 640 blocks: ct = b%5 col-tile, yc = b/5 64-row chunk.
// Col-tile 0 writes attn weights to d_out.
__global__ __launch_bounds__(256) void ctx_kernel(
    const float* __restrict__ enc, float* __restrict__ ws,
    float* __restrict__ out) {
  __shared__ float red[256];
  __shared__ float wsh[64];
  const float* sc = ws + OFF_SC;
  int t = threadIdx.x, b = blockIdx.x;
  float m = -3.4e38f;
  for (int i = t; i < S; i += 256) m = fmaxf(m, sc[i]);
  red[t] = m; __syncthreads();
  for (int off = 128; off; off >>= 1) {
    if (t < off) red[t] = fmaxf(red[t], red[t + off]);
    __syncthreads();
  }
  m = red[0]; __syncthreads();
  float s = 0.f;
  for (int i = t; i < S; i += 256) s += expf(sc[i] - m);
  red[t] = s; __syncthreads();
  for (int off = 128; off; off >>= 1) {
    if (t < off) red[t] += red[t + off];
    __syncthreads();
  }
  float inv = 1.f / red[0];
  int ct = b % 5, yc = b / 5;
  int s0 = yc * 64;
  if (t < 64) wsh[t] = expf(sc[s0 + t] - m) * inv;
  __syncthreads();
  if (ct == 0 && t < 64) out[O_ATTN + s0 + t] = wsh[t];
  int k = ct * 256 + t;
  if (k < H) {
    float acc = 0.f;
    for (int si = 0; si < 64; ++si) acc += wsh[si] * enc[(size_t)(s0 + si) * H + k];
    atomicAdd(ws + OFF_CTXV + k, acc);
  }
}

// K5: logits[r] = [hnew|ctx] . W_out[r,:] + b_out[r] -> d_out[0:V] (raw) +
// per-block online lse partials. Block 0 also emits ctx to d_out.
__global__ __launch_bounds__(256) void logits_kernel(
    const float* __restrict__ W_out, const float* __restrict__ b_out,
    float* __restrict__ ws, float* __restrict__ out) {
  __shared__ __align__(16) float joined[INW];
  __shared__ float pm[4], psv[4];
  int t = threadIdx.x, wv = t >> 6, lane = t & 63;
  for (int k = t; k < H; k += 256) {
    joined[k]     = (ws + OFF_HNEW)[k];
    joined[H + k] = (ws + OFF_CTXV)[k];
  }
  __syncthreads();
  if (blockIdx.x == 0) {
    for (int k = t; k < H; k += 256) out[O_CTX + k] = joined[H + k];
  }
  const float4* j4 = (const float4*)joined;
  int gw = blockIdx.x * 4 + wv;
  float lm = -3.4e38f, ls = 0.f;
  for (int r = gw; r < V; r += NPART * 4) {
    const float4* row = (const float4*)(W_out + (size_t)r * INW);
    float acc = 0.f;
    for (int i = lane; i < INW / 4; i += 64) acc += dot4(row[i], j4[i]);  // 516 f4
    acc = waveReduceSum(acc);
    if (lane == 0) {
      float x = acc + b_out[r];
      out[r] = x;
      float nm = fmaxf(lm, x);
      ls = ls * expf(lm - nm) + expf(x - nm);
      lm = nm;
    }
  }
  if (lane == 0) { pm[wv] = lm; psv[wv] = ls; }
  __syncthreads();
  if (t == 0) {
    float m = pm[0], sb = psv[0];
    for (int q = 1; q < 4; ++q) {
      float nm = fmaxf(m, pm[q]);
      sb = sb * expf(m - nm) + psv[q] * expf(pm[q] - nm);
      m = nm;
    }
    (ws + OFF_PART)[2 * blockIdx.x]     = m;
    (ws + OFF_PART)[2 * blockIdx.x + 1] = sb;
  }
}

// K6: combine partials (redundantly per block, deterministic) + subtract lse.
__global__ __launch_bounds__(256) void apply_kernel(
    float* __restrict__ out, const float* __restrict__ ws) {
  __shared__ float mm[256], ssv[256];
  const float* partials = ws + OFF_PART;
  int t = threadIdx.x;
  float m = -3.4e38f, s = 0.f;
  for (int i = t; i < NPART; i += 256) {
    float bm = partials[2 * i], bs = partials[2 * i + 1];
    float nm = fmaxf(m, bm);
    s = s * expf(m - nm) + bs * expf(bm - nm);
    m = nm;
  }
  mm[t] = m; ssv[t] = s; __syncthreads();
  for (int off = 128; off; off >>= 1) {
    if (t < off) {
      float m2 = mm[t + off], s2 = ssv[t + off];
      float nm = fmaxf(mm[t], m2);
      ssv[t] = ssv[t] * expf(mm[t] - nm) + s2 * expf(m2 - nm);
      mm[t] = nm;
    }
    __syncthreads();
  }
  float L = mm[0] + logf(ssv[0]);
  int i = blockIdx.x * 256 + t;
  if (i < V) out[i] -= L;
}

extern "C" void kernel_launch(void* const* d_in, const int* in_sizes, int n_in,
                              void* d_out, int out_size, void* d_ws, size_t ws_size,
                              hipStream_t stream) {
  const int*   word  = (const int*)d_in[0];
  const float* lc    = (const float*)d_in[1];
  const float* ph    = (const float*)d_in[2];
  const float* enc   = (const float*)d_in[3];
  const float* emb   = (const float*)d_in[4];
  const float* W_ih  = (const float*)d_in[5];
  const float* W_hh  = (const float*)d_in[6];
  const float* b_ih  = (const float*)d_in[7];
  const float* b_hh  = (const float*)d_in[8];
  const float* W_a   = (const float*)d_in[9];
  // d_in[10] = b_a: unused — constant shift of all attention scores, cancels in softmax.
  const float* W_out = (const float*)d_in[11];
  const float* b_out = (const float*)d_in[12];
  float* out = (float*)d_out;
  float* ws  = (float*)d_ws;

  gru_mv_kernel<<<GRU_B, 256, 0, stream>>>(word, emb, lc, ph, W_ih, W_hh, ws);
  vafin_kernel<<<VA_B + 4, 256, 0, stream>>>(W_a, ph, b_ih, b_hh, ws, out);
  scores_kernel<<<2048, 256, 0, stream>>>(enc, ws);
  ctx_kernel<<<640, 256, 0, stream>>>(enc, ws, out);
  logits_kernel<<<NPART, 256, 0, stream>>>(W_out, b_out, ws, out);
  apply_kernel<<<(V + 255) / 256, 256, 0, stream>>>(out, ws);
}

// Round 8
// 140.070 us; speedup vs baseline: 6.9381x; 1.0246x over previous
//
#include <hip/hip_runtime.h>
#include <math.h>

#define V  50257
#define H  1032
#define INW 2064
#define S  8192

// d_out flat layout (fp32): [output V][attn_context H][hidden H][attn_w S]
#define O_CTX  50257
#define O_HID  51289
#define O_ATTN 52321

// ws float offsets
#define OFF_GXP  0        // 2*3096 gx partials (chunk-major)
#define OFF_GHP  6192     // 2*3096 gh partials
#define OFF_HNEW 12384    // 1032
#define OFF_V    13416    // 1032 (zeroed by K1 block 0)
#define OFF_CTXV 14448    // 1032 (zeroed by K1 block 1)
#define OFF_SC   15480    // 8192 scores
#define OFF_SCP  23672    // 2*1024 score softmax partials (m,s)
#define OFF_PART 25720    // 2*NPART lse partials

#define GRU_B   1548      // 6192 waves = 3096 rows x 2 K-chunks
#define VA_B    80        // 5 col-tiles x 16 j-chunks
#define SC_B    1024      // scores blocks: 4 waves x 2 rows = 8 rows/block
#define NPART   2048      // logits blocks / partial pairs

__device__ __forceinline__ float waveReduceSum(float v) {
#pragma unroll
  for (int off = 32; off > 0; off >>= 1) v += __shfl_down(v, off);
  return v;  // valid in lane 0
}

__device__ __forceinline__ float dot4(const float4 a, const float4 b) {
  return a.x * b.x + a.y * b.y + a.z * b.z + a.w * b.w;
}

// K1: GRU matvec partials. Wave g = b*4+wv: row j = g>>1, K-chunk c = g&1.
// Blocks 0/1 zero v/ctxv for later atomics.
__global__ __launch_bounds__(256) void gru_mv_kernel(
    const int* __restrict__ word, const float* __restrict__ emb,
    const float* __restrict__ lc, const float* __restrict__ ph,
    const float* __restrict__ W_ih, const float* __restrict__ W_hh,
    float* __restrict__ ws) {
  __shared__ __align__(16) float xh[INW + H];
  float* gxp = ws + OFF_GXP;
  float* ghp = ws + OFF_GHP;
  int t = threadIdx.x, wv = t >> 6, lane = t & 63, b = blockIdx.x;
  if (b == 0) for (int i = t; i < H; i += 256) (ws + OFF_V)[i] = 0.f;
  if (b == 1) for (int i = t; i < H; i += 256) (ws + OFF_CTXV)[i] = 0.f;
  int w0 = word[0];
  for (int i = t; i < INW; i += 256) xh[i] = (i < H) ? emb[(size_t)w0 * H + i] : lc[i - H];
  for (int i = t; i < H; i += 256) xh[INW + i] = ph[i];
  __syncthreads();
  int g = b * 4 + wv;            // [0, 6192)
  int j = g >> 1, c = g & 1;     // row, K-chunk
  const float4* wi = (const float4*)(W_ih + (size_t)j * INW + c * (INW / 2));
  const float4* x4 = (const float4*)(xh + c * (INW / 2));
  float a0 = 0.f;
  for (int i = lane; i < INW / 8; i += 64) a0 += dot4(wi[i], x4[i]);   // 258 f4
  const float4* wh = (const float4*)(W_hh + (size_t)j * H + c * (H / 2));
  const float4* h4 = (const float4*)(xh + INW + c * (H / 2));
  float a1 = 0.f;
  for (int i = lane; i < H / 8; i += 64) a1 += dot4(wh[i], h4[i]);     // 129 f4
  a0 = waveReduceSum(a0); a1 = waveReduceSum(a1);
  if (lane == 0) { gxp[c * 3096 + j] = a0; ghp[c * 3096 + j] = a1; }
}

__device__ __forceinline__ float gru_elem(
    const float* __restrict__ gxp, const float* __restrict__ ghp,
    const float* __restrict__ b_ih, const float* __restrict__ b_hh,
    const float* __restrict__ ph, int k) {
  float gxr = gxp[k] + gxp[3096 + k],           ghr = ghp[k] + ghp[3096 + k];
  float gxz = gxp[H + k] + gxp[3096 + H + k],   ghz = ghp[H + k] + ghp[3096 + H + k];
  float gxn = gxp[2 * H + k] + gxp[3096 + 2 * H + k];
  float ghn = ghp[2 * H + k] + ghp[3096 + 2 * H + k];
  float r = 1.f / (1.f + expf(-(gxr + ghr + b_ih[k] + b_hh[k])));
  float z = 1.f / (1.f + expf(-(gxz + ghz + b_ih[H + k] + b_hh[H + k])));
  float n = tanhf(gxn + b_ih[2 * H + k] + r * (ghn + b_hh[2 * H + k]));
  return (1.f - z) * n + z * ph[k];
}

// K2: blocks [0,VA_B): v += W_a^T hnew (hnew slice finalized redundantly in-block);
// blocks [VA_B, VA_B+4): finalize + write hnew/hid_out.
__global__ __launch_bounds__(256) void vafin_kernel(
    const float* __restrict__ W_a, const float* __restrict__ ph,
    const float* __restrict__ b_ih, const float* __restrict__ b_hh,
    float* __restrict__ ws, float* __restrict__ out) {
  __shared__ float hsh[65];
  const float* gxp = ws + OFF_GXP;
  const float* ghp = ws + OFF_GHP;
  int b = blockIdx.x, t = threadIdx.x;
  if (b < VA_B) {
    int ct = b % 5, jc = b / 5;
    int j0 = jc * 65;
    int nj = min(65, H - j0);
    if (t < nj) hsh[t] = gru_elem(gxp, ghp, b_ih, b_hh, ph, j0 + t);
    __syncthreads();
    int k = ct * 256 + t;
    if (k < H) {
      float acc = 0.f;
      for (int j = 0; j < nj; ++j) acc += W_a[(size_t)(j0 + j) * H + k] * hsh[j];
      atomicAdd(ws + OFF_V + k, acc);
    }
  } else {
    int base = (b - VA_B) * 258;
    for (int kk = t; kk < 258; kk += 256) {
      int k = base + kk;
      float hv = gru_elem(gxp, ghp, b_ih, b_hh, ph, k);
      (ws + OFF_HNEW)[k] = hv;
      out[O_HID + k] = hv;
    }
  }
}

// K3: scores, 2 consecutive rows per wave (dual-stream ILP) + per-block
// softmax partial (m_b, s_b) over its 8 scores.  (b_a dropped: cancels in softmax)
__global__ __launch_bounds__(256) void scores_kernel(
    const float* __restrict__ enc, float* __restrict__ ws) {
  __shared__ float wm[4], wsv[4];
  int t = threadIdx.x, wv = t >> 6, lane = t & 63;
  int s0 = blockIdx.x * 8 + wv * 2;
  const float4* R0 = (const float4*)(enc + (size_t)s0 * H);
  const float4* R1 = (const float4*)(enc + (size_t)(s0 + 1) * H);
  const float4* v4 = (const float4*)(ws + OFF_V);
  float a0 = 0.f, a1 = 0.f;
  for (int i = lane; i < H / 4; i += 64) {
    float4 c = v4[i];
    a0 += dot4(R0[i], c);
    a1 += dot4(R1[i], c);
  }
  a0 = waveReduceSum(a0); a1 = waveReduceSum(a1);
  if (lane == 0) {
    (ws + OFF_SC)[s0]     = a0;
    (ws + OFF_SC)[s0 + 1] = a1;
    float m = fmaxf(a0, a1);
    wm[wv] = m;
    wsv[wv] = expf(a0 - m) + expf(a1 - m);
  }
  __syncthreads();
  if (t == 0) {
    float m = wm[0], s = wsv[0];
    for (int q = 1; q < 4; ++q) {
      float nm = fmaxf(m, wm[q]);
      s = s * expf(m - nm) + wsv[q] * expf(wm[q] - nm);
      m = nm;
    }
    (ws + OFF_SCP)[2 * blockIdx.x]     = m;
    (ws + OFF_SCP)[2 * blockIdx.x + 1] = s;
  }
}

// K4: ctx[k] = sum_s w[s]*enc[s][k]; softmax (M, Sigma) rebuilt per block from the
// 1024 (m,s) partials (deterministic). 640 blocks: ct=b%5 col-tile, yc=b/5 row chunk.
// Col-tile 0 writes attn weights to d_out.
__global__ __launch_bounds__(256) void ctx_kernel(
    const float* __restrict__ enc, float* __restrict__ ws,
    float* __restrict__ out) {
  __shared__ float rm[256], rs[256];
  __shared__ float wsh[64];
  const float* scp = ws + OFF_SCP;
  const float* sc  = ws + OFF_SC;
  int t = threadIdx.x, b = blockIdx.x;
  float m = -3.4e38f, s = 0.f;
  for (int i = t; i < SC_B; i += 256) {
    float bm = scp[2 * i], bs = scp[2 * i + 1];
    float nm = fmaxf(m, bm);
    s = s * expf(m - nm) + bs * expf(bm - nm);
    m = nm;
  }
  rm[t] = m; rs[t] = s; __syncthreads();
  for (int off = 128; off; off >>= 1) {
    if (t < off) {
      float m2 = rm[t + off], s2 = rs[t + off];
      float nm = fmaxf(rm[t], m2);
      rs[t] = rs[t] * expf(rm[t] - nm) + s2 * expf(m2 - nm);
      rm[t] = nm;
    }
    __syncthreads();
  }
  float M = rm[0];
  float inv = 1.f / rs[0];
  int ct = b % 5, yc = b / 5;
  int s0 = yc * 64;
  if (t < 64) wsh[t] = expf(sc[s0 + t] - M) * inv;
  __syncthreads();
  if (ct == 0 && t < 64) out[O_ATTN + s0 + t] = wsh[t];
  int k = ct * 256 + t;
  if (k < H) {
    float acc = 0.f;
    for (int si = 0; si < 64; ++si) acc += wsh[si] * enc[(size_t)(s0 + si) * H + k];
    atomicAdd(ws + OFF_CTXV + k, acc);
  }
}

// K5: logits, 2 consecutive full rows per wave (dual-stream ILP), sweep stride 16384.
// Raw logits -> d_out[0:V]; per-block online lse partials. Block 0 emits ctx.
__global__ __launch_bounds__(256) void logits_kernel(
    const float* __restrict__ W_out, const float* __restrict__ b_out,
    float* __restrict__ ws, float* __restrict__ out) {
  __shared__ __align__(16) float joined[INW];
  __shared__ float pm[4], psv[4];
  int t = threadIdx.x, wv = t >> 6, lane = t & 63;
  for (int k = t; k < H; k += 256) {
    joined[k]     = (ws + OFF_HNEW)[k];
    joined[H + k] = (ws + OFF_CTXV)[k];
  }
  __syncthreads();
  if (blockIdx.x == 0) {
    for (int k = t; k < H; k += 256) out[O_CTX + k] = joined[H + k];
  }
  const float4* j4 = (const float4*)joined;
  int gw = blockIdx.x * 4 + wv;  // [0, 8192)
  float lm = -3.4e38f, ls = 0.f;
  for (int r0 = gw * 2; r0 < V; r0 += 2 * NPART * 4) {
    int r1 = min(r0 + 1, V - 1);  // clamp (single odd tail row duplicates load)
    const float4* R0 = (const float4*)(W_out + (size_t)r0 * INW);
    const float4* R1 = (const float4*)(W_out + (size_t)r1 * INW);
    float a0 = 0.f, a1 = 0.f;
    for (int i = lane; i < INW / 4; i += 64) {  // 516 f4, two streams
      float4 c = j4[i];
      a0 += dot4(R0[i], c);
      a1 += dot4(R1[i], c);
    }
    a0 = waveReduceSum(a0); a1 = waveReduceSum(a1);
    if (lane == 0) {
      float x0 = a0 + b_out[r0];
      out[r0] = x0;
      float nm = fmaxf(lm, x0);
      ls = ls * expf(lm - nm) + expf(x0 - nm);
      lm = nm;
      if (r0 + 1 < V) {
        float x1 = a1 + b_out[r1];
        out[r1] = x1;
        nm = fmaxf(lm, x1);
        ls = ls * expf(lm - nm) + expf(x1 - nm);
        lm = nm;
      }
    }
  }
  if (lane == 0) { pm[wv] = lm; psv[wv] = ls; }
  __syncthreads();
  if (t == 0) {
    float m = pm[0], sb = psv[0];
    for (int q = 1; q < 4; ++q) {
      float nm = fmaxf(m, pm[q]);
      sb = sb * expf(m - nm) + psv[q] * expf(pm[q] - nm);
      m = nm;
    }
    (ws + OFF_PART)[2 * blockIdx.x]     = m;
    (ws + OFF_PART)[2 * blockIdx.x + 1] = sb;
  }
}

// K6: combine partials (redundantly per block, deterministic) + subtract lse.
__global__ __launch_bounds__(256) void apply_kernel(
    float* __restrict__ out, const float* __restrict__ ws) {
  __shared__ float mm[256], ssv[256];
  const float* partials = ws + OFF_PART;
  int t = threadIdx.x;
  float m = -3.4e38f, s = 0.f;
  for (int i = t; i < NPART; i += 256) {
    float bm = partials[2 * i], bs = partials[2 * i + 1];
    float nm = fmaxf(m, bm);
    s = s * expf(m - nm) + bs * expf(bm - nm);
    m = nm;
  }
  mm[t] = m; ssv[t] = s; __syncthreads();
  for (int off = 128; off; off >>= 1) {
    if (t < off) {
      float m2 = mm[t + off], s2 = ssv[t + off];
      float nm = fmaxf(mm[t], m2);
      ssv[t] = ssv[t] * expf(mm[t] - nm) + s2 * expf(m2 - nm);
      mm[t] = nm;
    }
    __syncthreads();
  }
  float L = mm[0] + logf(ssv[0]);
  int i = blockIdx.x * 256 + t;
  if (i < V) out[i] -= L;
}

extern "C" void kernel_launch(void* const* d_in, const int* in_sizes, int n_in,
                              void* d_out, int out_size, void* d_ws, size_t ws_size,
                              hipStream_t stream) {
  const int*   word  = (const int*)d_in[0];
  const float* lc    = (const float*)d_in[1];
  const float* ph    = (const float*)d_in[2];
  const float* enc   = (const float*)d_in[3];
  const float* emb   = (const float*)d_in[4];
  const float* W_ih  = (const float*)d_in[5];
  const float* W_hh  = (const float*)d_in[6];
  const float* b_ih  = (const float*)d_in[7];
  const float* b_hh  = (const float*)d_in[8];
  const float* W_a   = (const float*)d_in[9];
  // d_in[10] = b_a: unused — constant shift of all attention scores, cancels in softmax.
  const float* W_out = (const float*)d_in[11];
  const float* b_out = (const float*)d_in[12];
  float* out = (float*)d_out;
  float* ws  = (float*)d_ws;

  gru_mv_kernel<<<GRU_B, 256, 0, stream>>>(word, emb, lc, ph, W_ih, W_hh, ws);
  vafin_kernel<<<VA_B + 4, 256, 0, stream>>>(W_a, ph, b_ih, b_hh, ws, out);
  scores_kernel<<<SC_B, 256, 0, stream>>>(enc, ws);
  ctx_kernel<<<640, 256, 0, stream>>>(enc, ws, out);
  logits_kernel<<<NPART, 256, 0, stream>>>(W_out, b_out, ws, out);
  apply_kernel<<<(V + 255) / 256, 256, 0, stream>>>(out, ws);
}

// Round 9
// 131.046 us; speedup vs baseline: 7.4159x; 1.0689x over previous
//
#include <hip/hip_runtime.h>
#include <math.h>

#define V  50257
#define H  1032
#define INW 2064
#define S  8192

// d_out flat layout (fp32): [output V][attn_context H][hidden H][attn_w S]
#define O_CTX  50257
#define O_HID  51289
#define O_ATTN 52321

// ws float offsets
#define OFF_GXP  0        // 2*3096 gx partials (chunk-major)
#define OFF_GHP  6192     // 2*3096 gh partials
#define OFF_HNEW 12384    // 1032
#define OFF_V    13416    // 1032 (zeroed by K1 block 0)
#define OFF_CTXV 14448    // 1032 (zeroed by K1 block 1)
#define OFF_SC   15480    // 8192 scores
#define OFF_SCP  23672    // 2*1024 score softmax partials (m,s)
#define OFF_PART 25720    // 2*NPART lse partials

#define GRU_B   1548      // 6192 waves = 3096 rows x 2 K-chunks
#define VA_B    160       // 5 col-tiles x 32 j-chunks (33 rows each)
#define SC_B    1024      // scores blocks: 4 waves x 2 rows = 8 rows/block
#define NPART   2048      // logits blocks / partial pairs

typedef float fvec4 __attribute__((ext_vector_type(4)));

__device__ __forceinline__ float waveReduceSum(float v) {
#pragma unroll
  for (int off = 32; off > 0; off >>= 1) v += __shfl_down(v, off);
  return v;  // valid in lane 0
}

__device__ __forceinline__ float dot4(const float4 a, const float4 b) {
  return a.x * b.x + a.y * b.y + a.z * b.z + a.w * b.w;
}

// streamed-once load: nontemporal float4 dot against cached vector
__device__ __forceinline__ float ntdot(const fvec4* __restrict__ p, const float4 c) {
  fvec4 a = __builtin_nontemporal_load(p);
  return a.x * c.x + a.y * c.y + a.z * c.z + a.w * c.w;
}

// K1: GRU matvec partials. Wave g = b*4+wv: row j = g>>1, K-chunk c = g&1.
// Blocks 0/1 zero v/ctxv for later atomics.
__global__ __launch_bounds__(256) void gru_mv_kernel(
    const int* __restrict__ word, const float* __restrict__ emb,
    const float* __restrict__ lc, const float* __restrict__ ph,
    const float* __restrict__ W_ih, const float* __restrict__ W_hh,
    float* __restrict__ ws) {
  __shared__ __align__(16) float xh[INW + H];
  float* gxp = ws + OFF_GXP;
  float* ghp = ws + OFF_GHP;
  int t = threadIdx.x, wv = t >> 6, lane = t & 63, b = blockIdx.x;
  if (b == 0) for (int i = t; i < H; i += 256) (ws + OFF_V)[i] = 0.f;
  if (b == 1) for (int i = t; i < H; i += 256) (ws + OFF_CTXV)[i] = 0.f;
  int w0 = word[0];
  for (int i = t; i < INW; i += 256) xh[i] = (i < H) ? emb[(size_t)w0 * H + i] : lc[i - H];
  for (int i = t; i < H; i += 256) xh[INW + i] = ph[i];
  __syncthreads();
  int g = b * 4 + wv;            // [0, 6192)
  int j = g >> 1, c = g & 1;     // row, K-chunk
  const fvec4* wi = (const fvec4*)(W_ih + (size_t)j * INW + c * (INW / 2));
  const float4* x4 = (const float4*)(xh + c * (INW / 2));
  float a0 = 0.f;
  for (int i = lane; i < INW / 8; i += 64) a0 += ntdot(wi + i, x4[i]);   // 258 f4
  const fvec4* wh = (const fvec4*)(W_hh + (size_t)j * H + c * (H / 2));
  const float4* h4 = (const float4*)(xh + INW + c * (H / 2));
  float a1 = 0.f;
  for (int i = lane; i < H / 8; i += 64) a1 += ntdot(wh + i, h4[i]);     // 129 f4
  a0 = waveReduceSum(a0); a1 = waveReduceSum(a1);
  if (lane == 0) { gxp[c * 3096 + j] = a0; ghp[c * 3096 + j] = a1; }
}

__device__ __forceinline__ float gru_elem(
    const float* __restrict__ gxp, const float* __restrict__ ghp,
    const float* __restrict__ b_ih, const float* __restrict__ b_hh,
    const float* __restrict__ ph, int k) {
  float gxr = gxp[k] + gxp[3096 + k],           ghr = ghp[k] + ghp[3096 + k];
  float gxz = gxp[H + k] + gxp[3096 + H + k],   ghz = ghp[H + k] + ghp[3096 + H + k];
  float gxn = gxp[2 * H + k] + gxp[3096 + 2 * H + k];
  float ghn = ghp[2 * H + k] + ghp[3096 + 2 * H + k];
  float r = 1.f / (1.f + expf(-(gxr + ghr + b_ih[k] + b_hh[k])));
  float z = 1.f / (1.f + expf(-(gxz + ghz + b_ih[H + k] + b_hh[H + k])));
  float n = tanhf(gxn + b_ih[2 * H + k] + r * (ghn + b_hh[2 * H + k]));
  return (1.f - z) * n + z * ph[k];
}

// K2: blocks [0,VA_B): v += W_a^T hnew (hnew slice finalized redundantly in-block);
// blocks [VA_B, VA_B+4): finalize + write hnew/hid_out.
__global__ __launch_bounds__(256) void vafin_kernel(
    const float* __restrict__ W_a, const float* __restrict__ ph,
    const float* __restrict__ b_ih, const float* __restrict__ b_hh,
    float* __restrict__ ws, float* __restrict__ out) {
  __shared__ float hsh[33];
  const float* gxp = ws + OFF_GXP;
  const float* ghp = ws + OFF_GHP;
  int b = blockIdx.x, t = threadIdx.x;
  if (b < VA_B) {
    int ct = b % 5, jc = b / 5;        // jc in [0,32)
    int j0 = jc * 33;
    int nj = min(33, H - j0);
    if (t < nj) hsh[t] = gru_elem(gxp, ghp, b_ih, b_hh, ph, j0 + t);
    __syncthreads();
    int k = ct * 256 + t;
    if (k < H) {
      float acc = 0.f;
      for (int j = 0; j < nj; ++j)
        acc += __builtin_nontemporal_load(&W_a[(size_t)(j0 + j) * H + k]) * hsh[j];
      atomicAdd(ws + OFF_V + k, acc);
    }
  } else {
    int base = (b - VA_B) * 258;
    for (int kk = t; kk < 258; kk += 256) {
      int k = base + kk;
      float hv = gru_elem(gxp, ghp, b_ih, b_hh, ph, k);
      (ws + OFF_HNEW)[k] = hv;
      out[O_HID + k] = hv;
    }
  }
}

// K3: scores, 2 consecutive rows per wave + per-block softmax partial (m_b, s_b).
// enc stays cached (re-read by ctx). (b_a dropped: cancels in softmax)
__global__ __launch_bounds__(256) void scores_kernel(
    const float* __restrict__ enc, float* __restrict__ ws) {
  __shared__ float wm[4], wsv[4];
  int t = threadIdx.x, wv = t >> 6, lane = t & 63;
  int s0 = blockIdx.x * 8 + wv * 2;
  const float4* R0 = (const float4*)(enc + (size_t)s0 * H);
  const float4* R1 = (const float4*)(enc + (size_t)(s0 + 1) * H);
  const float4* v4 = (const float4*)(ws + OFF_V);
  float a0 = 0.f, a1 = 0.f;
  for (int i = lane; i < H / 4; i += 64) {
    float4 c = v4[i];
    a0 += dot4(R0[i], c);
    a1 += dot4(R1[i], c);
  }
  a0 = waveReduceSum(a0); a1 = waveReduceSum(a1);
  if (lane == 0) {
    (ws + OFF_SC)[s0]     = a0;
    (ws + OFF_SC)[s0 + 1] = a1;
    float m = fmaxf(a0, a1);
    wm[wv] = m;
    wsv[wv] = expf(a0 - m) + expf(a1 - m);
  }
  __syncthreads();
  if (t == 0) {
    float m = wm[0], s = wsv[0];
    for (int q = 1; q < 4; ++q) {
      float nm = fmaxf(m, wm[q]);
      s = s * expf(m - nm) + wsv[q] * expf(wm[q] - nm);
      m = nm;
    }
    (ws + OFF_SCP)[2 * blockIdx.x]     = m;
    (ws + OFF_SCP)[2 * blockIdx.x + 1] = s;
  }
}

// K4: ctx[k] = sum_s w[s]*enc[s][k]; softmax (M, Sigma) rebuilt per block from the
// 1024 (m,s) partials (deterministic). 640 blocks: ct=b%5 col-tile, yc=b/5 row chunk.
// Col-tile 0 writes attn weights to d_out. enc read is last use -> nontemporal.
__global__ __launch_bounds__(256) void ctx_kernel(
    const float* __restrict__ enc, float* __restrict__ ws,
    float* __restrict__ out) {
  __shared__ float rm[256], rs[256];
  __shared__ float wsh[64];
  const float* scp = ws + OFF_SCP;
  const float* sc  = ws + OFF_SC;
  int t = threadIdx.x, b = blockIdx.x;
  float m = -3.4e38f, s = 0.f;
  for (int i = t; i < SC_B; i += 256) {
    float bm = scp[2 * i], bs = scp[2 * i + 1];
    float nm = fmaxf(m, bm);
    s = s * expf(m - nm) + bs * expf(bm - nm);
    m = nm;
  }
  rm[t] = m; rs[t] = s; __syncthreads();
  for (int off = 128; off; off >>= 1) {
    if (t < off) {
      float m2 = rm[t + off], s2 = rs[t + off];
      float nm = fmaxf(rm[t], m2);
      rs[t] = rs[t] * expf(rm[t] - nm) + s2 * expf(m2 - nm);
      rm[t] = nm;
    }
    __syncthreads();
  }
  float M = rm[0];
  float inv = 1.f / rs[0];
  int ct = b % 5, yc = b / 5;
  int s0 = yc * 64;
  if (t < 64) wsh[t] = expf(sc[s0 + t] - M) * inv;
  __syncthreads();
  if (ct == 0 && t < 64) out[O_ATTN + s0 + t] = wsh[t];
  int k = ct * 256 + t;
  if (k < H) {
    float acc = 0.f;
    for (int si = 0; si < 64; ++si)
      acc += wsh[si] * __builtin_nontemporal_load(&enc[(size_t)(s0 + si) * H + k]);
    atomicAdd(ws + OFF_CTXV + k, acc);
  }
}

// K5: logits, 4 consecutive full rows per wave (quad-stream ILP, nt loads),
// sweep stride 32768. Raw logits -> d_out[0:V]; per-block lse partials.
// Block 0 emits ctx to d_out.
__global__ __launch_bounds__(256) void logits_kernel(
    const float* __restrict__ W_out, const float* __restrict__ b_out,
    float* __restrict__ ws, float* __restrict__ out) {
  __shared__ __align__(16) float joined[INW];
  __shared__ float pm[4], psv[4];
  int t = threadIdx.x, wv = t >> 6, lane = t & 63;
  for (int k = t; k < H; k += 256) {
    joined[k]     = (ws + OFF_HNEW)[k];
    joined[H + k] = (ws + OFF_CTXV)[k];
  }
  __syncthreads();
  if (blockIdx.x == 0) {
    for (int k = t; k < H; k += 256) out[O_CTX + k] = joined[H + k];
  }
  const float4* j4 = (const float4*)joined;
  int gw = blockIdx.x * 4 + wv;  // [0, 8192)
  float lm = -3.4e38f, ls = 0.f;
  for (int r0 = gw * 4; r0 < V; r0 += 4 * NPART * 4) {
    int rc1 = min(r0 + 1, V - 1), rc2 = min(r0 + 2, V - 1), rc3 = min(r0 + 3, V - 1);
    const fvec4* R0 = (const fvec4*)(W_out + (size_t)r0 * INW);
    const fvec4* R1 = (const fvec4*)(W_out + (size_t)rc1 * INW);
    const fvec4* R2 = (const fvec4*)(W_out + (size_t)rc2 * INW);
    const fvec4* R3 = (const fvec4*)(W_out + (size_t)rc3 * INW);
    float a0 = 0.f, a1 = 0.f, a2 = 0.f, a3 = 0.f;
    for (int i = lane; i < INW / 4; i += 64) {  // 516 f4, four streams
      float4 c = j4[i];
      a0 += ntdot(R0 + i, c);
      a1 += ntdot(R1 + i, c);
      a2 += ntdot(R2 + i, c);
      a3 += ntdot(R3 + i, c);
    }
    a0 = waveReduceSum(a0); a1 = waveReduceSum(a1);
    a2 = waveReduceSum(a2); a3 = waveReduceSum(a3);
    if (lane == 0) {
      float av[4] = {a0, a1, a2, a3};
#pragma unroll
      for (int q = 0; q < 4; ++q) {
        int r = r0 + q;
        if (r < V) {
          float x = av[q] + b_out[r];
          out[r] = x;
          float nm = fmaxf(lm, x);
          ls = ls * expf(lm - nm) + expf(x - nm);
          lm = nm;
        }
      }
    }
  }
  if (lane == 0) { pm[wv] = lm; psv[wv] = ls; }
  __syncthreads();
  if (t == 0) {
    float m = pm[0], sb = psv[0];
    for (int q = 1; q < 4; ++q) {
      float nm = fmaxf(m, pm[q]);
      sb = sb * expf(m - nm) + psv[q] * expf(pm[q] - nm);
      m = nm;
    }
    (ws + OFF_PART)[2 * blockIdx.x]     = m;
    (ws + OFF_PART)[2 * blockIdx.x + 1] = sb;
  }
}

// K6: combine partials (redundantly per block, deterministic) + subtract lse.
__global__ __launch_bounds__(256) void apply_kernel(
    float* __restrict__ out, const float* __restrict__ ws) {
  __shared__ float mm[256], ssv[256];
  const float* partials = ws + OFF_PART;
  int t = threadIdx.x;
  float m = -3.4e38f, s = 0.f;
  for (int i = t; i < NPART; i += 256) {
    float bm = partials[2 * i], bs = partials[2 * i + 1];
    float nm = fmaxf(m, bm);
    s = s * expf(m - nm) + bs * expf(bm - nm);
    m = nm;
  }
  mm[t] = m; ssv[t] = s; __syncthreads();
  for (int off = 128; off; off >>= 1) {
    if (t < off) {
      float m2 = mm[t + off], s2 = ssv[t + off];
      float nm = fmaxf(mm[t], m2);
      ssv[t] = ssv[t] * expf(mm[t] - nm) + s2 * expf(m2 - nm);
      mm[t] = nm;
    }
    __syncthreads();
  }
  float L = mm[0] + logf(ssv[0]);
  int i = blockIdx.x * 256 + t;
  if (i < V) out[i] -= L;
}

extern "C" void kernel_launch(void* const* d_in, const int* in_sizes, int n_in,
                              void* d_out, int out_size, void* d_ws, size_t ws_size,
                              hipStream_t stream) {
  const int*   word  = (const int*)d_in[0];
  const float* lc    = (const float*)d_in[1];
  const float* ph    = (const float*)d_in[2];
  const float* enc   = (const float*)d_in[3];
  const float* emb   = (const float*)d_in[4];
  const float* W_ih  = (const float*)d_in[5];
  const float* W_hh  = (const float*)d_in[6];
  const float* b_ih  = (const float*)d_in[7];
  const float* b_hh  = (const float*)d_in[8];
  const float* W_a   = (const float*)d_in[9];
  // d_in[10] = b_a: unused — constant shift of all attention scores, cancels in softmax.
  const float* W_out = (const float*)d_in[11];
  const float* b_out = (const float*)d_in[12];
  float* out = (float*)d_out;
  float* ws  = (float*)d_ws;

  gru_mv_kernel<<<GRU_B, 256, 0, stream>>>(word, emb, lc, ph, W_ih, W_hh, ws);
  vafin_kernel<<<VA_B + 4, 256, 0, stream>>>(W_a, ph, b_ih, b_hh, ws, out);
  scores_kernel<<<SC_B, 256, 0, stream>>>(enc, ws);
  ctx_kernel<<<640, 256, 0, stream>>>(enc, ws, out);
  logits_kernel<<<NPART, 256, 0, stream>>>(W_out, b_out, ws, out);
  apply_kernel<<<(V + 255) / 256, 256, 0, stream>>>(out, ws);
}